// Round 1
// baseline (779.262 us; speedup 1.0000x reference)
//
#include <hip/hip_runtime.h>

#define N_NODES 100000
#define DIM 128
#define N_REL 8
#define N_EDGES 625000

// fp32 -> bf16, round-to-nearest-even
__device__ __forceinline__ unsigned short f2bf(float f) {
    unsigned int u = __float_as_uint(f);
    u += 0x7fffu + ((u >> 16) & 1u);
    return (unsigned short)(u >> 16);
}

__device__ __forceinline__ float bf2f(unsigned short s) {
    return __uint_as_float(((unsigned int)s) << 16);
}

// Wt[r][dout][din] <- rel_weight[r][din][dout] (r<8), self_loop[din][dout] (r==8), as bf16
__global__ __launch_bounds__(256) void convert_w_kernel(const float* __restrict__ relw,
                                                        const float* __restrict__ selfw,
                                                        unsigned short* __restrict__ Wt) {
    int i = blockIdx.x * 256 + threadIdx.x;       // i = r*16384 + dout*128 + din
    int r = i >> 14;
    int rem = i & 16383;
    int dout = rem >> 7;
    int din = rem & 127;
    float v = (r < 8) ? relw[(r << 14) + (din << 7) + dout] : selfw[(din << 7) + dout];
    Wt[i] = f2bf(v);
}

__global__ __launch_bounds__(256) void deg_kernel(const int* __restrict__ dst,
                                                  const int* __restrict__ rel,
                                                  float* __restrict__ deg) {
    int e = blockIdx.x * 256 + threadIdx.x;
    if (e < N_EDGES) atomicAdd(&deg[rel[e] * N_NODES + dst[e]], 1.0f);
}

// Per block: 64 rows x 128 cols of (x @ W_r). blockIdx.y = r in [0,9).
// r<8: write bf16 to xW[r]; r==8: write fp32 out = acc + bias (self-loop term).
typedef __attribute__((ext_vector_type(8))) short frag8;
typedef __attribute__((ext_vector_type(4))) float f32x4;

__global__ __launch_bounds__(256) void gemm_kernel(const float* __restrict__ x,
                                                   const unsigned short* __restrict__ Wt,
                                                   unsigned short* __restrict__ xW,
                                                   float* __restrict__ out,
                                                   const float* __restrict__ bias) {
    __shared__ __align__(16) unsigned short lds[64 * 136 + 128 * 136]; // A then B(t), 52.2 KB
    unsigned short* Alds = lds;
    unsigned short* Blds = lds + 64 * 136;

    const int r = blockIdx.y;
    const int row0 = blockIdx.x * 64;
    const int tid = threadIdx.x;

    // Stage A: 64 rows x 128 cols, read fp32 x, convert to bf16. 1024 chunks of 8 elems.
    for (int c = tid; c < 1024; c += 256) {
        int row = c >> 4, off = (c & 15) * 8;
        int grow = row0 + row;
        unsigned short tmp[8];
        if (grow < N_NODES) {
            const float* p = x + (size_t)grow * DIM + off;
            float4 a = *(const float4*)p;
            float4 b = *(const float4*)(p + 4);
            tmp[0] = f2bf(a.x); tmp[1] = f2bf(a.y); tmp[2] = f2bf(a.z); tmp[3] = f2bf(a.w);
            tmp[4] = f2bf(b.x); tmp[5] = f2bf(b.y); tmp[6] = f2bf(b.z); tmp[7] = f2bf(b.w);
        } else {
            for (int j = 0; j < 8; j++) tmp[j] = 0;
        }
        *(uint4*)(Alds + row * 136 + off) = *(uint4*)tmp;
    }
    // Stage B: Wt[r] = [dout][din] 128x128 bf16, straight copy. 2048 chunks of 8.
    const unsigned short* Wr = Wt + (size_t)r * DIM * DIM;
    for (int c = tid; c < 2048; c += 256) {
        int row = c >> 4, off = (c & 15) * 8;
        *(uint4*)(Blds + row * 136 + off) = *(const uint4*)(Wr + row * DIM + off);
    }
    __syncthreads();

    const int wave = tid >> 6, lane = tid & 63;
    const int m16 = lane & 15, quad = lane >> 4;
    const int arow = wave * 16 + m16;

    f32x4 acc[8];
#pragma unroll
    for (int t = 0; t < 8; t++) acc[t] = (f32x4){0.f, 0.f, 0.f, 0.f};

#pragma unroll
    for (int ks = 0; ks < 4; ks++) {
        int k0 = ks * 32 + quad * 8;
        frag8 a = *(const frag8*)(Alds + arow * 136 + k0);
#pragma unroll
        for (int t = 0; t < 8; t++) {
            frag8 b = *(const frag8*)(Blds + (t * 16 + m16) * 136 + k0);
            acc[t] = __builtin_amdgcn_mfma_f32_16x16x32_bf16(a, b, acc[t], 0, 0, 0);
        }
    }
    __syncthreads(); // all waves done reading A/B before LDS reuse

    if (r < 8) {
        // Repack acc -> LDS bf16 [64][128], then coalesced 16B stores.
        unsigned short* S = lds;
#pragma unroll
        for (int t = 0; t < 8; t++) {
            int col = t * 16 + m16;
#pragma unroll
            for (int i = 0; i < 4; i++) {
                int row = wave * 16 + quad * 4 + i;
                S[row * 128 + col] = f2bf(acc[t][i]);
            }
        }
        __syncthreads();
        for (int c = tid; c < 1024; c += 256) {
            int row = c >> 4, off = (c & 15) * 8;
            int grow = row0 + row;
            if (grow < N_NODES)
                *(uint4*)(xW + ((size_t)r * N_NODES + grow) * DIM + off) = *(uint4*)(S + row * 128 + off);
        }
    } else {
        // Self-loop term: out = acc + bias, fp32 via LDS repack.
        float* S = (float*)lds; // 8192 floats = 32 KB, fits
#pragma unroll
        for (int t = 0; t < 8; t++) {
            int col = t * 16 + m16;
            float bcol = bias[col];
#pragma unroll
            for (int i = 0; i < 4; i++) {
                int row = wave * 16 + quad * 4 + i;
                S[row * 128 + col] = acc[t][i] + bcol;
            }
        }
        __syncthreads();
        for (int c = tid; c < 2048; c += 256) {
            int row = c >> 5, off = (c & 31) * 4;
            int grow = row0 + row;
            if (grow < N_NODES)
                *(uint4*)(out + (size_t)grow * DIM + off) = *(uint4*)(S + row * 128 + off);
        }
    }
}

// One wave per edge: gather xW[rel][src] (2 bf16/lane), scale by 1/deg, atomicAdd into out[dst].
__global__ __launch_bounds__(256) void scatter_kernel(const unsigned short* __restrict__ xW,
                                                      const int* __restrict__ src,
                                                      const int* __restrict__ dst,
                                                      const int* __restrict__ rel,
                                                      const float* __restrict__ deg,
                                                      float* __restrict__ out) {
    int wave = threadIdx.x >> 6, lane = threadIdx.x & 63;
    int e = blockIdx.x * 4 + wave;
    if (e >= N_EDGES) return;
    int s = src[e], d = dst[e], r = rel[e];
    float dg = deg[r * N_NODES + d];
    float inv = 1.0f / fmaxf(dg, 1.0f);
    const unsigned short* row = xW + ((size_t)r * N_NODES + s) * DIM;
    unsigned int u = *(const unsigned int*)(row + lane * 2); // 2 bf16
    float lo = bf2f((unsigned short)(u & 0xffffu)) * inv;
    float hi = bf2f((unsigned short)(u >> 16)) * inv;
    float* o = out + (size_t)d * DIM + lane * 2;
    atomicAdd(o, lo);
    atomicAdd(o + 1, hi);
}

extern "C" void kernel_launch(void* const* d_in, const int* in_sizes, int n_in,
                              void* d_out, int out_size, void* d_ws, size_t ws_size,
                              hipStream_t stream) {
    const float* x = (const float*)d_in[0];
    const int* edge_index = (const int*)d_in[1]; // [2][E]: src then dst
    const int* edge_type = (const int*)d_in[2];
    const float* relw = (const float*)d_in[3];
    const float* selfw = (const float*)d_in[4];
    const float* bias = (const float*)d_in[5];
    float* out = (float*)d_out;
    (void)in_sizes; (void)n_in; (void)out_size; (void)ws_size;

    char* ws = (char*)d_ws;
    size_t off = 0;
    unsigned short* xW = (unsigned short*)(ws + off); off += (size_t)N_REL * N_NODES * DIM * 2; // 204.8 MB
    unsigned short* Wt = (unsigned short*)(ws + off); off += (size_t)9 * DIM * DIM * 2;         // 0.3 MB
    float* deg = (float*)(ws + off); off += (size_t)N_REL * N_NODES * 4;                        // 3.2 MB

    const int* src = edge_index;
    const int* dst = edge_index + N_EDGES;

    hipMemsetAsync(deg, 0, (size_t)N_REL * N_NODES * 4, stream);
    convert_w_kernel<<<576, 256, 0, stream>>>(relw, selfw, Wt);
    deg_kernel<<<(N_EDGES + 255) / 256, 256, 0, stream>>>(dst, edge_type, deg);
    gemm_kernel<<<dim3((N_NODES + 63) / 64, 9), 256, 0, stream>>>(x, Wt, xW, out, bias);
    scatter_kernel<<<N_EDGES / 4, 256, 0, stream>>>(xW, src, dst, edge_type, deg, out);
}

// Round 2
// 395.694 us; speedup vs baseline: 1.9694x; 1.9694x over previous
//
#include <hip/hip_runtime.h>

#define N_NODES 100000
#define DIM 128
#define N_REL 8
#define N_EDGES 625000
#define PAD_N 100352   // 392 * 256
#define NCHUNK 392

// fp32 -> bf16, round-to-nearest-even
__device__ __forceinline__ unsigned short f2bf(float f) {
    unsigned int u = __float_as_uint(f);
    u += 0x7fffu + ((u >> 16) & 1u);
    return (unsigned short)(u >> 16);
}

__device__ __forceinline__ float bf2f(unsigned short s) {
    return __uint_as_float(((unsigned int)s) << 16);
}

// Wt[r][dout][din] <- rel_weight[r][din][dout] (r<8), self_loop[din][dout] (r==8), as bf16
__global__ __launch_bounds__(256) void convert_w_kernel(const float* __restrict__ relw,
                                                        const float* __restrict__ selfw,
                                                        unsigned short* __restrict__ Wt) {
    int i = blockIdx.x * 256 + threadIdx.x;       // i = r*16384 + dout*128 + din
    int r = i >> 14;
    int rem = i & 16383;
    int dout = rem >> 7;
    int din = rem & 127;
    float v = (r < 8) ? relw[(r << 14) + (din << 7) + dout] : selfw[(din << 7) + dout];
    Wt[i] = f2bf(v);
}

// Per-(rel,dst) degree + per-dst in-degree histogram (int atomics, ~1.25M total).
__global__ __launch_bounds__(256) void hist_kernel(const int* __restrict__ dst,
                                                   const int* __restrict__ rel,
                                                   int* __restrict__ degi,
                                                   int* __restrict__ cnt) {
    int e = blockIdx.x * 256 + threadIdx.x;
    if (e < N_EDGES) {
        int d = dst[e], r = rel[e];
        atomicAdd(&degi[r * N_NODES + d], 1);
        atomicAdd(&cnt[d], 1);
    }
}

// Block sums of cnt (256-chunks) -> bsum[392]
__global__ __launch_bounds__(256) void scan1_kernel(const int* __restrict__ cnt,
                                                    int* __restrict__ bsum) {
    __shared__ int l[256];
    int t = threadIdx.x;
    l[t] = cnt[blockIdx.x * 256 + t];
    __syncthreads();
    for (int off = 128; off > 0; off >>= 1) {
        if (t < off) l[t] += l[t + off];
        __syncthreads();
    }
    if (t == 0) bsum[blockIdx.x] = l[0];
}

// Exclusive scan of bsum[392] in place (single block; serial in LDS is ~µs)
__global__ __launch_bounds__(512) void scan2_kernel(int* __restrict__ bsum) {
    __shared__ int l[NCHUNK];
    int t = threadIdx.x;
    if (t < NCHUNK) l[t] = bsum[t];
    __syncthreads();
    if (t == 0) {
        int run = 0;
        for (int i = 0; i < NCHUNK; i++) { int v = l[i]; l[i] = run; run += v; }
    }
    __syncthreads();
    if (t < NCHUNK) bsum[t] = l[t];
}

// Per-element exclusive scan -> offs (persists in ws) and cursor (scratch copy)
__global__ __launch_bounds__(256) void scan3_kernel(const int* __restrict__ cnt,
                                                    const int* __restrict__ bsum,
                                                    int* __restrict__ offs,
                                                    int* __restrict__ cursor) {
    __shared__ int l[256];
    int t = threadIdx.x;
    int i = blockIdx.x * 256 + t;
    int c = cnt[i];
    l[t] = c;
    __syncthreads();
    for (int off = 1; off < 256; off <<= 1) {   // Hillis-Steele inclusive
        int v = (t >= off) ? l[t - off] : 0;
        __syncthreads();
        l[t] += v;
        __syncthreads();
    }
    int excl = l[t] - c + bsum[blockIdx.x];
    offs[i] = excl;
    cursor[i] = excl;
}

// Bin edges by dst; pack (src | rel<<17 | deg<<20) into one uint32 per slot.
__global__ __launch_bounds__(256) void fill_kernel(const int* __restrict__ src,
                                                   const int* __restrict__ dst,
                                                   const int* __restrict__ rel,
                                                   const int* __restrict__ degi,
                                                   int* __restrict__ cursor,
                                                   unsigned int* __restrict__ ebuf) {
    int e = blockIdx.x * 256 + threadIdx.x;
    if (e < N_EDGES) {
        int d = dst[e], r = rel[e], s = src[e];
        int pos = atomicAdd(&cursor[d], 1);
        int dg = degi[r * N_NODES + d];
        if (dg > 4095) dg = 4095;
        ebuf[pos] = (unsigned int)s | ((unsigned int)r << 17) | ((unsigned int)dg << 20);
    }
}

// One block = 64 rows; stage A (x->bf16) once, loop r over 9 weights.
// r<8: bf16 to xW[r]; r==8: fp32 out = acc + bias (self-loop term).
typedef __attribute__((ext_vector_type(8))) short frag8;
typedef __attribute__((ext_vector_type(4))) float f32x4;

__global__ __launch_bounds__(256) void gemm_kernel(const float* __restrict__ x,
                                                   const unsigned short* __restrict__ Wt,
                                                   unsigned short* __restrict__ xW,
                                                   float* __restrict__ out,
                                                   const float* __restrict__ bias) {
    __shared__ __align__(16) unsigned short Alds[64 * 136];   // 17.4 KB
    __shared__ __align__(16) unsigned short Blds[128 * 136];  // 34.8 KB (reused as repack S)

    const int row0 = blockIdx.x * 64;
    const int tid = threadIdx.x;

    // Stage A once: 64 rows x 128 cols fp32 -> bf16
    for (int c = tid; c < 1024; c += 256) {
        int row = c >> 4, off = (c & 15) * 8;
        int grow = row0 + row;
        unsigned short tmp[8];
        if (grow < N_NODES) {
            const float* p = x + (size_t)grow * DIM + off;
            float4 a = *(const float4*)p;
            float4 b = *(const float4*)(p + 4);
            tmp[0] = f2bf(a.x); tmp[1] = f2bf(a.y); tmp[2] = f2bf(a.z); tmp[3] = f2bf(a.w);
            tmp[4] = f2bf(b.x); tmp[5] = f2bf(b.y); tmp[6] = f2bf(b.z); tmp[7] = f2bf(b.w);
        } else {
            for (int j = 0; j < 8; j++) tmp[j] = 0;
        }
        *(uint4*)(Alds + row * 136 + off) = *(uint4*)tmp;
    }
    __syncthreads();

    const int wave = tid >> 6, lane = tid & 63;
    const int m16 = lane & 15, quad = lane >> 4;
    const int arow = wave * 16 + m16;

    frag8 a[4];
#pragma unroll
    for (int ks = 0; ks < 4; ks++)
        a[ks] = *(const frag8*)(Alds + arow * 136 + ks * 32 + quad * 8);

    for (int r = 0; r < 9; r++) {
        const unsigned short* Wr = Wt + r * 16384;
        for (int c = tid; c < 2048; c += 256) {
            int row = c >> 4, off = (c & 15) * 8;
            *(uint4*)(Blds + row * 136 + off) = *(const uint4*)(Wr + row * DIM + off);
        }
        __syncthreads();

        f32x4 acc[8];
#pragma unroll
        for (int t = 0; t < 8; t++) acc[t] = (f32x4){0.f, 0.f, 0.f, 0.f};
#pragma unroll
        for (int ks = 0; ks < 4; ks++) {
            int k0 = ks * 32 + quad * 8;
#pragma unroll
            for (int t = 0; t < 8; t++) {
                frag8 b = *(const frag8*)(Blds + (t * 16 + m16) * 136 + k0);
                acc[t] = __builtin_amdgcn_mfma_f32_16x16x32_bf16(a[ks], b, acc[t], 0, 0, 0);
            }
        }
        __syncthreads();  // B reads done before repack overwrites Blds

        if (r < 8) {
            unsigned short* S = Blds;  // 64 x 136 bf16 repack
#pragma unroll
            for (int t = 0; t < 8; t++) {
                int col = t * 16 + m16;
#pragma unroll
                for (int i = 0; i < 4; i++)
                    S[(wave * 16 + quad * 4 + i) * 136 + col] = f2bf(acc[t][i]);
            }
            __syncthreads();
            for (int c = tid; c < 1024; c += 256) {
                int row = c >> 4, off = (c & 15) * 8;
                int grow = row0 + row;
                if (grow < N_NODES)
                    *(uint4*)(xW + ((size_t)r * N_NODES + grow) * DIM + off) =
                        *(uint4*)(S + row * 136 + off);
            }
        } else {
            float* S = (float*)Blds;   // 64 x 132 fp32 repack (33.8 KB fits)
#pragma unroll
            for (int t = 0; t < 8; t++) {
                int col = t * 16 + m16;
                float bcol = bias[col];
#pragma unroll
                for (int i = 0; i < 4; i++)
                    S[(wave * 16 + quad * 4 + i) * 132 + col] = acc[t][i] + bcol;
            }
            __syncthreads();
            for (int c = tid; c < 2048; c += 256) {
                int row = c >> 5, off = (c & 31) * 4;
                int grow = row0 + row;
                if (grow < N_NODES)
                    *(uint4*)(out + (size_t)grow * DIM + off) = *(uint4*)(S + row * 132 + off);
            }
        }
        __syncthreads();  // stores read Blds; next iter staging overwrites
    }
}

// One wave per dst: sum messages from CSR, single non-atomic RMW of out[dst].
__global__ __launch_bounds__(256) void gather_kernel(const unsigned short* __restrict__ xW,
                                                     const int* __restrict__ offs,
                                                     const unsigned int* __restrict__ ebuf,
                                                     float* __restrict__ out) {
    int wave = threadIdx.x >> 6, lane = threadIdx.x & 63;
    int d = blockIdx.x * 4 + wave;
    if (d >= N_NODES) return;
    int start = offs[d], end = offs[d + 1];
    if (start == end) return;
    float sx = 0.f, sy = 0.f;
    for (int i = start; i < end; i++) {
        unsigned int u = ebuf[i];
        int s = u & 0x1ffff;
        int r = (u >> 17) & 7;
        float inv = 1.0f / (float)(u >> 20);
        const unsigned int* row = (const unsigned int*)(xW + ((size_t)(r * N_NODES + s)) * DIM);
        unsigned int v = row[lane];  // 2 bf16 per lane, 256B/wave coalesced
        sx += inv * bf2f((unsigned short)(v & 0xffffu));
        sy += inv * bf2f((unsigned short)(v >> 16));
    }
    float2* o = (float2*)(out + (size_t)d * DIM) + lane;
    float2 cur = *o;
    cur.x += sx; cur.y += sy;
    *o = cur;
}

extern "C" void kernel_launch(void* const* d_in, const int* in_sizes, int n_in,
                              void* d_out, int out_size, void* d_ws, size_t ws_size,
                              hipStream_t stream) {
    const float* x = (const float*)d_in[0];
    const int* edge_index = (const int*)d_in[1]; // [2][E]: src then dst
    const int* edge_type = (const int*)d_in[2];
    const float* relw = (const float*)d_in[3];
    const float* selfw = (const float*)d_in[4];
    const float* bias = (const float*)d_in[5];
    float* out = (float*)d_out;
    (void)in_sizes; (void)n_in; (void)out_size; (void)ws_size;

    // ws layout (207.996 MB total, < round-1's proven 208.3 MB):
    char* ws = (char*)d_ws;
    size_t off = 0;
    unsigned short* xW = (unsigned short*)(ws + off); off += (size_t)N_REL * N_NODES * DIM * 2; // 204.8 MB
    unsigned short* Wt = (unsigned short*)(ws + off); off += (size_t)9 * DIM * DIM * 2;         // 0.29 MB
    int* offs = (int*)(ws + off); off += (size_t)PAD_N * 4;                                     // 0.40 MB
    unsigned int* ebuf = (unsigned int*)(ws + off); off += (size_t)N_EDGES * 4;                 // 2.5 MB

    // Pre-GEMM-dead scratch lives in d_out (51.2 MB); everything reading it
    // completes (stream-ordered) before gemm_kernel writes out.
    char* ob = (char*)d_out;
    int* degi = (int*)ob;                                   // 3.2 MB
    int* cnt = (int*)(ob + (size_t)N_REL * N_NODES * 4);    // 0.40 MB
    int* cursor = cnt + PAD_N;                              // 0.40 MB
    int* bsum = cursor + PAD_N;                             // 1.6 KB

    const int* src = edge_index;
    const int* dst = edge_index + N_EDGES;

    hipMemsetAsync(degi, 0, (size_t)N_REL * N_NODES * 4, stream);
    hipMemsetAsync(cnt, 0, (size_t)PAD_N * 4, stream);
    convert_w_kernel<<<576, 256, 0, stream>>>(relw, selfw, Wt);
    hist_kernel<<<(N_EDGES + 255) / 256, 256, 0, stream>>>(dst, edge_type, degi, cnt);
    scan1_kernel<<<NCHUNK, 256, 0, stream>>>(cnt, bsum);
    scan2_kernel<<<1, 512, 0, stream>>>(bsum);
    scan3_kernel<<<NCHUNK, 256, 0, stream>>>(cnt, bsum, offs, cursor);
    fill_kernel<<<(N_EDGES + 255) / 256, 256, 0, stream>>>(src, dst, edge_type, degi, cursor, ebuf);
    gemm_kernel<<<(N_NODES + 63) / 64, 256, 0, stream>>>(x, Wt, xW, out, bias);
    gather_kernel<<<(N_NODES + 3) / 4, 256, 0, stream>>>(xW, offs, ebuf, out);
}

// Round 3
// 363.023 us; speedup vs baseline: 2.1466x; 1.0900x over previous
//
#include <hip/hip_runtime.h>

#define N_NODES 100000
#define DIM 128
#define N_REL 8
#define N_EDGES 625000
#define PAD_N 100352   // 392 * 256
#define NCHUNK 392

// fp32 -> bf16, round-to-nearest-even
__device__ __forceinline__ unsigned short f2bf(float f) {
    unsigned int u = __float_as_uint(f);
    u += 0x7fffu + ((u >> 16) & 1u);
    return (unsigned short)(u >> 16);
}

__device__ __forceinline__ float bf2f(unsigned short s) {
    return __uint_as_float(((unsigned int)s) << 16);
}

// Wt in MFMA B-fragment order:
// Wt[((r*4+ks)*8 + t)*64 + lane]*8 + j] = W_r[din=ks*32+quad*8+j][dout=t*16+m16]
// (r==8 -> self_loop). A wave's frag (r,ks,t) is then 64 lanes x 16B contiguous.
__global__ __launch_bounds__(256) void convert_w_kernel(const float* __restrict__ relw,
                                                        const float* __restrict__ selfw,
                                                        unsigned short* __restrict__ Wt) {
    int i = blockIdx.x * 256 + threadIdx.x;   // 9*16384 = 147456 total
    int j = i & 7;
    int lane = (i >> 3) & 63;
    int t = (i >> 9) & 7;
    int ks = (i >> 12) & 3;
    int r = i >> 14;
    int m16 = lane & 15, quad = lane >> 4;
    int din = ks * 32 + quad * 8 + j;
    int dout = t * 16 + m16;
    float v = (r < 8) ? relw[(r << 14) + (din << 7) + dout] : selfw[(din << 7) + dout];
    Wt[i] = f2bf(v);
}

// Per-(rel,dst) degree + per-dst in-degree histogram (int atomics).
__global__ __launch_bounds__(256) void hist_kernel(const int* __restrict__ dst,
                                                   const int* __restrict__ rel,
                                                   int* __restrict__ degi,
                                                   int* __restrict__ cnt) {
    int e = blockIdx.x * 256 + threadIdx.x;
    if (e < N_EDGES) {
        int d = dst[e], r = rel[e];
        atomicAdd(&degi[r * N_NODES + d], 1);
        atomicAdd(&cnt[d], 1);
    }
}

__global__ __launch_bounds__(256) void scan1_kernel(const int* __restrict__ cnt,
                                                    int* __restrict__ bsum) {
    __shared__ int l[256];
    int t = threadIdx.x;
    l[t] = cnt[blockIdx.x * 256 + t];
    __syncthreads();
    for (int off = 128; off > 0; off >>= 1) {
        if (t < off) l[t] += l[t + off];
        __syncthreads();
    }
    if (t == 0) bsum[blockIdx.x] = l[0];
}

__global__ __launch_bounds__(512) void scan2_kernel(int* __restrict__ bsum) {
    __shared__ int l[NCHUNK];
    int t = threadIdx.x;
    if (t < NCHUNK) l[t] = bsum[t];
    __syncthreads();
    if (t == 0) {
        int run = 0;
        for (int i = 0; i < NCHUNK; i++) { int v = l[i]; l[i] = run; run += v; }
    }
    __syncthreads();
    if (t < NCHUNK) bsum[t] = l[t];
}

__global__ __launch_bounds__(256) void scan3_kernel(const int* __restrict__ cnt,
                                                    const int* __restrict__ bsum,
                                                    int* __restrict__ offs,
                                                    int* __restrict__ cursor) {
    __shared__ int l[256];
    int t = threadIdx.x;
    int i = blockIdx.x * 256 + t;
    int c = cnt[i];
    l[t] = c;
    __syncthreads();
    for (int off = 1; off < 256; off <<= 1) {
        int v = (t >= off) ? l[t - off] : 0;
        __syncthreads();
        l[t] += v;
        __syncthreads();
    }
    int excl = l[t] - c + bsum[blockIdx.x];
    offs[i] = excl;
    cursor[i] = excl;
}

__global__ __launch_bounds__(256) void fill_kernel(const int* __restrict__ src,
                                                   const int* __restrict__ dst,
                                                   const int* __restrict__ rel,
                                                   const int* __restrict__ degi,
                                                   int* __restrict__ cursor,
                                                   unsigned int* __restrict__ ebuf) {
    int e = blockIdx.x * 256 + threadIdx.x;
    if (e < N_EDGES) {
        int d = dst[e], r = rel[e], s = src[e];
        int pos = atomicAdd(&cursor[d], 1);
        int dg = degi[r * N_NODES + d];
        if (dg > 4095) dg = 4095;
        ebuf[pos] = (unsigned int)s | ((unsigned int)r << 17) | ((unsigned int)dg << 20);
    }
}

typedef __attribute__((ext_vector_type(8))) short frag8;
typedef __attribute__((ext_vector_type(4))) float f32x4;

// One block = 64 rows. A staged to LDS once (1 barrier total); B-frags loaded
// coalesced from global (L2-hot, fragment-ordered Wt); per-r output repack is
// wave-private through the dead A-stage LDS (no barriers in the r loop).
__global__ __launch_bounds__(256, 4) void gemm_kernel(const float* __restrict__ x,
                                                      const unsigned short* __restrict__ Wt,
                                                      unsigned short* __restrict__ xW,
                                                      float* __restrict__ out,
                                                      const float* __restrict__ bias) {
    __shared__ __align__(16) unsigned short Alds[64 * 136];   // 17.4 KB total LDS

    const int row0 = blockIdx.x * 64;
    const int tid = threadIdx.x;

    // Stage A once: 64 rows x 128 cols fp32 -> bf16 (cross-wave -> 1 barrier).
    for (int c = tid; c < 1024; c += 256) {
        int row = c >> 4, off = (c & 15) * 8;
        int grow = row0 + row;
        unsigned short tmp[8];
        if (grow < N_NODES) {
            const float* p = x + (size_t)grow * DIM + off;
            float4 a = *(const float4*)p;
            float4 b = *(const float4*)(p + 4);
            tmp[0] = f2bf(a.x); tmp[1] = f2bf(a.y); tmp[2] = f2bf(a.z); tmp[3] = f2bf(a.w);
            tmp[4] = f2bf(b.x); tmp[5] = f2bf(b.y); tmp[6] = f2bf(b.z); tmp[7] = f2bf(b.w);
        } else {
            for (int j = 0; j < 8; j++) tmp[j] = 0;
        }
        *(uint4*)(Alds + row * 136 + off) = *(uint4*)tmp;
    }
    __syncthreads();

    const int wave = tid >> 6, lane = tid & 63;
    const int m16 = lane & 15, quad = lane >> 4;
    const int arow = wave * 16 + m16;

    // A frags to registers; A LDS is dead afterwards (rows are wave-private).
    frag8 a[4];
#pragma unroll
    for (int ks = 0; ks < 4; ks++)
        a[ks] = *(const frag8*)(Alds + arow * 136 + ks * 32 + quad * 8);

    // Wave-private repack slab = this wave's 16 A rows.
    unsigned short* S = Alds + wave * 16 * 136;
    const int grow_base = row0 + wave * 16;

#pragma unroll 1
    for (int r = 0; r < 8; r++) {
        f32x4 acc[8];
#pragma unroll
        for (int t = 0; t < 8; t++) acc[t] = (f32x4){0.f, 0.f, 0.f, 0.f};
#pragma unroll
        for (int ks = 0; ks < 4; ks++) {
            const frag8* bp = (const frag8*)Wt + ((r * 4 + ks) * 8) * 64 + lane;
            frag8 b[8];
#pragma unroll
            for (int t = 0; t < 8; t++) b[t] = bp[t * 64];
#pragma unroll
            for (int t = 0; t < 8; t++)
                acc[t] = __builtin_amdgcn_mfma_f32_16x16x32_bf16(a[ks], b[t], acc[t], 0, 0, 0);
        }
        // Wave-synchronous repack: C layout (row=quad*4+i, col=t*16+m16) -> row-major.
#pragma unroll
        for (int t = 0; t < 8; t++) {
            int col = t * 16 + m16;
#pragma unroll
            for (int i = 0; i < 4; i++)
                S[(quad * 4 + i) * 136 + col] = f2bf(acc[t][i]);
        }
#pragma unroll
        for (int c = 0; c < 4; c++) {
            int row16 = c * 4 + (lane >> 4);
            int grow = grow_base + row16;
            if (grow < N_NODES)
                *(uint4*)(xW + ((size_t)r * N_NODES + grow) * DIM + (lane & 15) * 8) =
                    *(uint4*)(S + row16 * 136 + (lane & 15) * 8);
        }
    }

    // Self-loop (r==8): out = acc + bias, fp32, two column-halves through the slab.
    {
        f32x4 acc[8];
#pragma unroll
        for (int t = 0; t < 8; t++) acc[t] = (f32x4){0.f, 0.f, 0.f, 0.f};
#pragma unroll
        for (int ks = 0; ks < 4; ks++) {
            const frag8* bp = (const frag8*)Wt + ((8 * 4 + ks) * 8) * 64 + lane;
            frag8 b[8];
#pragma unroll
            for (int t = 0; t < 8; t++) b[t] = bp[t * 64];
#pragma unroll
            for (int t = 0; t < 8; t++)
                acc[t] = __builtin_amdgcn_mfma_f32_16x16x32_bf16(a[ks], b[t], acc[t], 0, 0, 0);
        }
        float* S32 = (float*)Alds + wave * 16 * 68;  // 16 rows x 64 cols (+4 pad) fp32
#pragma unroll
        for (int h = 0; h < 2; h++) {
#pragma unroll
            for (int t2 = 0; t2 < 4; t2++) {
                int t = h * 4 + t2;
                float bc = bias[t * 16 + m16];
#pragma unroll
                for (int i = 0; i < 4; i++)
                    S32[(quad * 4 + i) * 68 + t2 * 16 + m16] = acc[t][i] + bc;
            }
#pragma unroll
            for (int c = 0; c < 4; c++) {
                int row16 = c * 4 + (lane >> 4);
                int grow = grow_base + row16;
                if (grow < N_NODES)
                    *(float4*)(out + (size_t)grow * DIM + h * 64 + (lane & 15) * 4) =
                        *(float4*)(S32 + row16 * 68 + (lane & 15) * 4);
            }
        }
    }
}

// One wave per dst: sum CSR messages (2-edge unrolled for MLP), non-atomic RMW.
__global__ __launch_bounds__(256) void gather_kernel(const unsigned short* __restrict__ xW,
                                                     const int* __restrict__ offs,
                                                     const unsigned int* __restrict__ ebuf,
                                                     float* __restrict__ out) {
    int wave = threadIdx.x >> 6, lane = threadIdx.x & 63;
    int d = blockIdx.x * 4 + wave;
    if (d >= N_NODES) return;
    int start = offs[d], end = offs[d + 1];
    if (start == end) return;
    float2* o = (float2*)(out + (size_t)d * DIM) + lane;
    float2 cur = *o;  // issue early; overlaps gather latency
    float sx = 0.f, sy = 0.f;
    int i = start;
    for (; i + 2 <= end; i += 2) {
        unsigned int u0 = ebuf[i], u1 = ebuf[i + 1];
        const unsigned int* r0 = (const unsigned int*)(xW +
            ((size_t)(((u0 >> 17) & 7) * N_NODES + (u0 & 0x1ffff))) * DIM);
        const unsigned int* r1 = (const unsigned int*)(xW +
            ((size_t)(((u1 >> 17) & 7) * N_NODES + (u1 & 0x1ffff))) * DIM);
        unsigned int v0 = r0[lane];
        unsigned int v1 = r1[lane];
        float inv0 = 1.0f / (float)(u0 >> 20);
        float inv1 = 1.0f / (float)(u1 >> 20);
        sx += inv0 * bf2f((unsigned short)(v0 & 0xffffu));
        sy += inv0 * bf2f((unsigned short)(v0 >> 16));
        sx += inv1 * bf2f((unsigned short)(v1 & 0xffffu));
        sy += inv1 * bf2f((unsigned short)(v1 >> 16));
    }
    if (i < end) {
        unsigned int u = ebuf[i];
        const unsigned int* rw = (const unsigned int*)(xW +
            ((size_t)(((u >> 17) & 7) * N_NODES + (u & 0x1ffff))) * DIM);
        unsigned int v = rw[lane];
        float inv = 1.0f / (float)(u >> 20);
        sx += inv * bf2f((unsigned short)(v & 0xffffu));
        sy += inv * bf2f((unsigned short)(v >> 16));
    }
    cur.x += sx; cur.y += sy;
    *o = cur;
}

extern "C" void kernel_launch(void* const* d_in, const int* in_sizes, int n_in,
                              void* d_out, int out_size, void* d_ws, size_t ws_size,
                              hipStream_t stream) {
    const float* x = (const float*)d_in[0];
    const int* edge_index = (const int*)d_in[1]; // [2][E]: src then dst
    const int* edge_type = (const int*)d_in[2];
    const float* relw = (const float*)d_in[3];
    const float* selfw = (const float*)d_in[4];
    const float* bias = (const float*)d_in[5];
    float* out = (float*)d_out;
    (void)in_sizes; (void)n_in; (void)out_size; (void)ws_size;

    char* ws = (char*)d_ws;
    size_t off = 0;
    unsigned short* xW = (unsigned short*)(ws + off); off += (size_t)N_REL * N_NODES * DIM * 2; // 204.8 MB
    unsigned short* Wt = (unsigned short*)(ws + off); off += (size_t)9 * DIM * DIM * 2;         // 0.29 MB
    int* offs = (int*)(ws + off); off += (size_t)PAD_N * 4;                                     // 0.40 MB
    unsigned int* ebuf = (unsigned int*)(ws + off); off += (size_t)N_EDGES * 4;                 // 2.5 MB

    // Pre-GEMM-dead scratch in d_out (gemm overwrites all of out afterwards).
    char* ob = (char*)d_out;
    int* degi = (int*)ob;                                   // 3.2 MB
    int* cnt = (int*)(ob + (size_t)N_REL * N_NODES * 4);    // 0.40 MB
    int* cursor = cnt + PAD_N;                              // 0.40 MB
    int* bsum = cursor + PAD_N;                             // 1.6 KB

    const int* src = edge_index;
    const int* dst = edge_index + N_EDGES;

    hipMemsetAsync(degi, 0, (size_t)N_REL * N_NODES * 4, stream);
    hipMemsetAsync(cnt, 0, (size_t)PAD_N * 4, stream);
    convert_w_kernel<<<576, 256, 0, stream>>>(relw, selfw, Wt);
    hist_kernel<<<(N_EDGES + 255) / 256, 256, 0, stream>>>(dst, edge_type, degi, cnt);
    scan1_kernel<<<NCHUNK, 256, 0, stream>>>(cnt, bsum);
    scan2_kernel<<<1, 512, 0, stream>>>(bsum);
    scan3_kernel<<<NCHUNK, 256, 0, stream>>>(cnt, bsum, offs, cursor);
    fill_kernel<<<(N_EDGES + 255) / 256, 256, 0, stream>>>(src, dst, edge_type, degi, cursor, ebuf);
    gemm_kernel<<<(N_NODES + 63) / 64, 256, 0, stream>>>(x, Wt, xW, out, bias);
    gather_kernel<<<(N_NODES + 3) / 4, 256, 0, stream>>>(xW, offs, ebuf, out);
}